// Round 1
// baseline (155.718 us; speedup 1.0000x reference)
//
#include <hip/hip_runtime.h>
#include <hip/hip_bf16.h>

// SimCLR NT-Xent loss on MI355X.
// loss = -(1/2B) sum_t [ 10*G[t,j0(t)] - (10 + log sum_{j!=t} exp(10*G[t,j]-10)) ]
// where G = M M^T, M = l2norm rows of [z_i; z_j], j0 = (t%B==0) ? 1 : 0.

#define BB 4096      // batch B
#define DD 512       // feature dim
#define NN 8192      // 2B rows of G
#define TILE 128     // block tile (rows x cols)
#define KC 64        // K staged per LDS chunk

typedef __attribute__((ext_vector_type(8))) short short8;
typedef __attribute__((ext_vector_type(4))) float f32x4;

// ---------------- kernel 1: L2-normalize rows, cast to bf16 ----------------
__global__ __launch_bounds__(256)
void normalize_kernel(const float* __restrict__ zi, const float* __restrict__ zj,
                      __hip_bfloat16* __restrict__ M) {
    const int row = blockIdx.x;                 // 0..8191
    const int tid = threadIdx.x;                // 0..255, 2 floats each
    const float* src = (row < BB) ? (zi + (size_t)row * DD)
                                  : (zj + (size_t)(row - BB) * DD);
    float2 v = ((const float2*)src)[tid];
    float ss = v.x * v.x + v.y * v.y;
    #pragma unroll
    for (int off = 32; off; off >>= 1) ss += __shfl_down(ss, off);
    __shared__ float red[4];
    if ((tid & 63) == 0) red[tid >> 6] = ss;
    __syncthreads();
    float tot = red[0] + red[1] + red[2] + red[3];
    float inv = rsqrtf(tot);
    __hip_bfloat162 o;
    o.x = __float2bfloat16(v.x * inv);
    o.y = __float2bfloat16(v.y * inv);
    ((__hip_bfloat162*)(M + (size_t)row * DD))[tid] = o;
}

// ---------------- kernel 2: Gram tile + exp row-sums (+ target capture) ----
// Grid: (64, 64) blocks of 256 threads. Each block: one 128x128 tile of G.
// Wave w: rows wr=(w>>1)*64, cols wc=(w&1)*64 within the tile (4x4 MFMA tiles).
__global__ __launch_bounds__(256, 2)
void gram_lse_kernel(const __hip_bfloat16* __restrict__ Mb,
                     float* __restrict__ rowsum, float* __restrict__ targets) {
    __shared__ __align__(16) short As[TILE * KC];   // 16 KB, XOR-swizzled granules
    __shared__ __align__(16) short Bs[TILE * KC];   // 16 KB

    const int rowBase = blockIdx.x * TILE;
    const int colBase = blockIdx.y * TILE;
    const int tid  = threadIdx.x;
    const int wave = tid >> 6;
    const int lane = tid & 63;
    const int wr = (wave >> 1) * 64;
    const int wc = (wave & 1) * 64;
    const int l15 = lane & 15;
    const int l4  = lane >> 4;          // quad 0..3

    const short* Mg = (const short*)Mb;

    f32x4 acc[4][4] = {};

    for (int k0 = 0; k0 < DD; k0 += KC) {
        __syncthreads();   // previous-iteration LDS reads done
        // stage 128 rows x 64 k of A and B. 1024 16B-granules each; 4 per thread.
        #pragma unroll
        for (int i = 0; i < 4; ++i) {
            int p   = tid + 256 * i;    // 0..1023
            int row = p >> 3;           // 8 granules per row
            int g   = p & 7;
            short8 av = *(const short8*)(Mg + (size_t)(rowBase + row) * DD + k0 + g * 8);
            ((short8*)As)[row * 8 + (g ^ (row & 7))] = av;
            short8 bv = *(const short8*)(Mg + (size_t)(colBase + row) * DD + k0 + g * 8);
            ((short8*)Bs)[row * 8 + (g ^ (row & 7))] = bv;
        }
        __syncthreads();
        #pragma unroll
        for (int ks = 0; ks < KC / 32; ++ks) {
            const int gk = ks * 4 + l4;         // granule index within row
            short8 a[4], b[4];
            #pragma unroll
            for (int mi = 0; mi < 4; ++mi) {
                int row = wr + mi * 16 + l15;
                a[mi] = ((const short8*)As)[row * 8 + (gk ^ (row & 7))];
            }
            #pragma unroll
            for (int ni = 0; ni < 4; ++ni) {
                int row = wc + ni * 16 + l15;
                b[ni] = ((const short8*)Bs)[row * 8 + (gk ^ (row & 7))];
            }
            #pragma unroll
            for (int mi = 0; mi < 4; ++mi)
                #pragma unroll
                for (int ni = 0; ni < 4; ++ni)
                    acc[mi][ni] = __builtin_amdgcn_mfma_f32_16x16x32_bf16(
                        a[mi], b[ni], acc[mi][ni], 0, 0, 0);
        }
    }

    // ---- epilogue: e = exp(10*g - 10), mask diagonal, reduce rows, atomics ----
    // C/D layout: col = lane&15, row = (lane>>4)*4 + reg   [verified m89/m91]
    #pragma unroll
    for (int mi = 0; mi < 4; ++mi) {
        float rs[4] = {0.f, 0.f, 0.f, 0.f};
        #pragma unroll
        for (int ni = 0; ni < 4; ++ni) {
            const int gcol = colBase + wc + ni * 16 + l15;
            #pragma unroll
            for (int r = 0; r < 4; ++r) {
                const int grow = rowBase + wr + mi * 16 + l4 * 4 + r;
                float logit = 10.f * acc[mi][ni][r];
                float e = __expf(logit - 10.f);
                if (grow == gcol) e = 0.f;     // exclude diagonal exactly
                rs[r] += e;
                // target: col j0 = (grow % B == 0) ? 1 : 0 ; lives in colTile 0
                const int j0 = ((grow & (BB - 1)) == 0) ? 1 : 0;
                if (gcol == j0) targets[grow] = logit;
            }
        }
        #pragma unroll
        for (int m = 1; m <= 8; m <<= 1)
            #pragma unroll
            for (int r = 0; r < 4; ++r)
                rs[r] += __shfl_xor(rs[r], m);
        if (l15 == 0) {
            #pragma unroll
            for (int r = 0; r < 4; ++r)
                atomicAdd(&rowsum[rowBase + wr + mi * 16 + l4 * 4 + r], rs[r]);
        }
    }
}

// ---------------- kernel 3: final scalar reduction -------------------------
__global__ __launch_bounds__(256)
void finalize_kernel(const float* __restrict__ rowsum,
                     const float* __restrict__ targets, float* __restrict__ out) {
    const int tid = threadIdx.x;
    float s = 0.f;
    for (int t = tid; t < NN; t += 256)
        s += targets[t] - 10.f - __logf(rowsum[t]);
    #pragma unroll
    for (int off = 32; off; off >>= 1) s += __shfl_down(s, off);
    __shared__ float red[4];
    if ((tid & 63) == 0) red[tid >> 6] = s;
    __syncthreads();
    if (tid == 0) out[0] = -(red[0] + red[1] + red[2] + red[3]) / (float)NN;
}

extern "C" void kernel_launch(void* const* d_in, const int* in_sizes, int n_in,
                              void* d_out, int out_size, void* d_ws, size_t ws_size,
                              hipStream_t stream) {
    const float* zi = (const float*)d_in[0];
    const float* zj = (const float*)d_in[1];

    __hip_bfloat16* M = (__hip_bfloat16*)d_ws;                       // 8 MB
    float* rowsum  = (float*)((char*)d_ws + (size_t)NN * DD * 2);    // 32 KB
    float* targets = rowsum + NN;                                    // 32 KB
    float* out = (float*)d_out;

    hipMemsetAsync(rowsum, 0, NN * sizeof(float), stream);
    normalize_kernel<<<NN, 256, 0, stream>>>(zi, zj, M);
    gram_lse_kernel<<<dim3(NN / TILE, NN / TILE), 256, 0, stream>>>(M, rowsum, targets);
    finalize_kernel<<<1, 256, 0, stream>>>(rowsum, targets, out);
}